// Round 1
// baseline (287.085 us; speedup 1.0000x reference)
//
#include <hip/hip_runtime.h>
#include <hip/hip_bf16.h>

#define DIM   1024
#define BATCH 8192
#define KV    16

typedef __attribute__((ext_vector_type(4))) float f32x4;
typedef __attribute__((ext_vector_type(8))) short short8;

static __device__ __forceinline__ unsigned short f2bf(float x) {
  return __builtin_bit_cast(unsigned short, __float2bfloat16(x));
}

static __device__ __forceinline__ void gl_lds16(const unsigned short* g, unsigned short* l) {
  __builtin_amdgcn_global_load_lds(
      (const __attribute__((address_space(1))) void*)g,
      (__attribute__((address_space(3))) void*)l, 16, 0, 0);
}

// ---------------- kernel 1: query f32 -> bf16 ----------------
__global__ __launch_bounds__(256) void convert_q(const float4* __restrict__ in,
                                                 ushort4* __restrict__ out, int n4) {
  int i = blockIdx.x * blockDim.x + threadIdx.x;
  int stride = gridDim.x * blockDim.x;
  for (; i < n4; i += stride) {
    float4 f = in[i];
    ushort4 o;
    o.x = f2bf(f.x); o.y = f2bf(f.y); o.z = f2bf(f.z); o.w = f2bf(f.w);
    out[i] = o;
  }
}

// ---------------- kernel 2: Wq,Wk f32 -> transposed bf16 ----------------
// dst[d][c] = src[c][d]  (1024x1024), z=0: Wq->WqT, z=1: Wk->WkT
__global__ __launch_bounds__(256) void transpose_w(const float* __restrict__ Wq,
                                                   const float* __restrict__ Wk,
                                                   unsigned short* __restrict__ WqT,
                                                   unsigned short* __restrict__ WkT) {
  __shared__ float tile[32][33];
  const float* src = blockIdx.z ? Wk : Wq;
  unsigned short* dst = blockIdx.z ? WkT : WqT;
  int x = blockIdx.x * 32 + threadIdx.x;   // src col
  int y0 = blockIdx.y * 32;                // src row base
  #pragma unroll
  for (int i = threadIdx.y; i < 32; i += 8)
    tile[i][threadIdx.x] = src[(size_t)(y0 + i) * DIM + x];
  __syncthreads();
  int x2 = blockIdx.y * 32 + threadIdx.x;  // dst col = src row
  int y2 = blockIdx.x * 32;                // dst row base = src col
  #pragma unroll
  for (int i = threadIdx.y; i < 32; i += 8)
    dst[(size_t)(y2 + i) * DIM + x2] = f2bf(tile[threadIdx.x][i]);
}

// ---------------- kernel 3/4: NT bf16 GEMM (m97 structure) ----------------
// C[m,n] = sum_k A[m,k] * B[n,k];  A:[M][K] bf16 row-major, B:[N][K] bf16 row-major
// BM=BN=128, BK=32, 4 waves (2x2), each wave 64x64 via 4x4 frags of 16x16x32 MFMA.
template<int BF16OUT>
__global__ __launch_bounds__(256) void gemm_nt(const unsigned short* __restrict__ A,
                                               const unsigned short* __restrict__ B,
                                               void* __restrict__ Cv,
                                               int M, int N, int K) {
  __shared__ __align__(16) unsigned short As[128 * 32];
  __shared__ __align__(16) unsigned short Bs[128 * 32];
  const int tid  = threadIdx.x;
  const int lane = tid & 63;
  const int wave = tid >> 6;
  const int wr = wave >> 1, wc = wave & 1;
  const size_t bm = (size_t)blockIdx.x * 128;
  const size_t bn = (size_t)blockIdx.y * 128;

  f32x4 acc[4][4];
  #pragma unroll
  for (int m = 0; m < 4; ++m)
    #pragma unroll
    for (int n = 0; n < 4; ++n)
      acc[m][n] = (f32x4){0.f, 0.f, 0.f, 0.f};

  // staging: 512 chunks of 16B per tile; chunk cid -> row=cid>>2, koff=(cid&3)*8
  const int r0 = tid >> 2;
  const int r1 = 64 + (tid >> 2);
  const int cc = (tid & 3) * 8;
  const int kg = lane >> 4;     // k-group for fragments
  const int rowf = lane & 15;

  for (int kt = 0; kt < K; kt += 32) {
    gl_lds16(A + (bm + r0) * K + kt + cc, As + tid * 8);
    gl_lds16(A + (bm + r1) * K + kt + cc, As + 2048 + tid * 8);
    gl_lds16(B + (bn + r0) * K + kt + cc, Bs + tid * 8);
    gl_lds16(B + (bn + r1) * K + kt + cc, Bs + 2048 + tid * 8);
    __syncthreads();   // drains vmcnt -> LDS tile ready
    short8 af[4], bfr[4];
    #pragma unroll
    for (int m = 0; m < 4; ++m)
      af[m] = *(const short8*)(As + ((wr * 64 + m * 16 + rowf) * 32 + kg * 8));
    #pragma unroll
    for (int n = 0; n < 4; ++n)
      bfr[n] = *(const short8*)(Bs + ((wc * 64 + n * 16 + rowf) * 32 + kg * 8));
    #pragma unroll
    for (int m = 0; m < 4; ++m)
      #pragma unroll
      for (int n = 0; n < 4; ++n)
        acc[m][n] = __builtin_amdgcn_mfma_f32_16x16x32_bf16(af[m], bfr[n], acc[m][n], 0, 0, 0);
    __syncthreads();   // frags consumed -> safe to overwrite LDS
  }

  const int rq = (lane >> 4) * 4;
  const int colf = lane & 15;
  #pragma unroll
  for (int m = 0; m < 4; ++m)
    #pragma unroll
    for (int n = 0; n < 4; ++n)
      #pragma unroll
      for (int i = 0; i < 4; ++i) {
        size_t row = bm + wr * 64 + m * 16 + rq + i;
        size_t col = bn + wc * 64 + n * 16 + colf;
        if (BF16OUT)
          ((unsigned short*)Cv)[row * N + col] = f2bf(acc[m][n][i]);
        else
          ((float*)Cv)[row * N + col] = acc[m][n][i];
      }
}

// ---------------- kernel 5: fused attention epilogue ----------------
// per batch b: scores_j = dot(u_b, k_j)/32 (k_0 = q_b), softmax, attn = sum wt_j v_j,
// alpha = sigmoid(dot(q_b, Wa)+ba), out = normalize(q_b + alpha*attn)
__global__ __launch_bounds__(256) void epilogue(const float* __restrict__ query,
                                                const float* __restrict__ key,
                                                const float* __restrict__ value,
                                                const float* __restrict__ Wa,
                                                const float* __restrict__ ba,
                                                const float* __restrict__ u,
                                                float* __restrict__ out) {
  const int b = blockIdx.x;
  const int tid = threadIdx.x;
  const int lane = tid & 63, wave = tid >> 6;
  const float4* q4 = (const float4*)(query + (size_t)b * DIM);
  const float4* u4 = (const float4*)(u + (size_t)b * DIM);
  const float4* k4 = (const float4*)(key + (size_t)b * KV * DIM);
  const float4* v4 = (const float4*)(value + (size_t)b * KV * DIM);

  float4 qv = q4[tid];
  float4 uv = u4[tid];
  float4 wv = ((const float4*)Wa)[tid];

  float s[17];
  s[0] = qv.x * uv.x + qv.y * uv.y + qv.z * uv.z + qv.w * uv.w;
  float ad = qv.x * wv.x + qv.y * wv.y + qv.z * wv.z + qv.w * wv.w;
  #pragma unroll
  for (int j = 1; j <= 16; ++j) {
    float4 kv = k4[(j - 1) * 256 + tid];
    s[j] = uv.x * kv.x + uv.y * kv.y + uv.z * kv.z + uv.w * kv.w;
  }

  // wave-level butterfly reduce of 18 scalars
  #pragma unroll
  for (int m = 32; m >= 1; m >>= 1) {
    #pragma unroll
    for (int j = 0; j < 17; ++j) s[j] += __shfl_xor(s[j], m);
    ad += __shfl_xor(ad, m);
  }
  __shared__ float red[4][18];
  if (lane == 0) {
    #pragma unroll
    for (int j = 0; j < 17; ++j) red[wave][j] = s[j];
    red[wave][17] = ad;
  }
  __syncthreads();

  float wt[17];
  float mx = -1e30f;
  #pragma unroll
  for (int j = 0; j < 17; ++j) {
    float t = (red[0][j] + red[1][j] + red[2][j] + red[3][j]) * 0.03125f;
    wt[j] = t;
    mx = fmaxf(mx, t);
  }
  float den = 0.f;
  #pragma unroll
  for (int j = 0; j < 17; ++j) {
    wt[j] = expf(wt[j] - mx);
    den += wt[j];
  }
  float adt = red[0][17] + red[1][17] + red[2][17] + red[3][17] + ba[0];
  float alpha = 1.0f / (1.0f + expf(-adt));
  float am = alpha / den;

  float4 acc;
  acc.x = wt[0] * qv.x; acc.y = wt[0] * qv.y; acc.z = wt[0] * qv.z; acc.w = wt[0] * qv.w;
  #pragma unroll
  for (int j = 1; j <= 16; ++j) {
    float4 vv = v4[(j - 1) * 256 + tid];
    acc.x += wt[j] * vv.x; acc.y += wt[j] * vv.y;
    acc.z += wt[j] * vv.z; acc.w += wt[j] * vv.w;
  }
  float4 t;
  t.x = qv.x + am * acc.x; t.y = qv.y + am * acc.y;
  t.z = qv.z + am * acc.z; t.w = qv.w + am * acc.w;

  float ssp = t.x * t.x + t.y * t.y + t.z * t.z + t.w * t.w;
  #pragma unroll
  for (int m = 32; m >= 1; m >>= 1) ssp += __shfl_xor(ssp, m);
  __shared__ float red2[4];
  if (lane == 0) red2[wave] = ssp;
  __syncthreads();
  float nrm = sqrtf(red2[0] + red2[1] + red2[2] + red2[3]);
  float inv = 1.0f / fmaxf(nrm, 1e-12f);

  float4 o;
  o.x = t.x * inv; o.y = t.y * inv; o.z = t.z * inv; o.w = t.w * inv;
  ((float4*)(out + (size_t)b * DIM))[tid] = o;
}

// ---------------- launcher ----------------
extern "C" void kernel_launch(void* const* d_in, const int* in_sizes, int n_in,
                              void* d_out, int out_size, void* d_ws, size_t ws_size,
                              hipStream_t stream) {
  const float* query = (const float*)d_in[0];
  const float* key   = (const float*)d_in[1];
  const float* value = (const float*)d_in[2];
  const float* Wq    = (const float*)d_in[3];
  const float* Wk    = (const float*)d_in[4];
  const float* Wa    = (const float*)d_in[5];
  const float* ba    = (const float*)d_in[6];

  unsigned short* qbf = (unsigned short*)d_ws;              // 16 MiB  (8192x1024 bf16)
  unsigned short* WqT = qbf + (size_t)BATCH * DIM;          //  2 MiB  WqT[d][c]=Wq[c][d]
  unsigned short* WkT = WqT + (size_t)DIM * DIM;            //  2 MiB  WkT[e][c]=Wk[c][e]
  unsigned short* Mt  = WkT + (size_t)DIM * DIM;            //  2 MiB  Mt[e][d]=sum_c Wk[c,e]Wq[c,d]

  // 1) conversions
  convert_q<<<2048, 256, 0, stream>>>((const float4*)query, (ushort4*)qbf, BATCH * DIM / 4);
  transpose_w<<<dim3(32, 32, 2), dim3(32, 8), 0, stream>>>(Wq, Wk, WqT, WkT);
  // 2) Mt = WkT x WqT^T  (1024^3, bf16 out)
  gemm_nt<1><<<dim3(8, 8), 256, 0, stream>>>(WkT, WqT, Mt, DIM, DIM, DIM);
  // 3) u = qbf x Mt^T  (8192x1024x1024, f32 out -> d_out, read back by epilogue)
  gemm_nt<0><<<dim3(BATCH / 128, DIM / 128), 256, 0, stream>>>(qbf, Mt, d_out, BATCH, DIM, DIM);
  // 4) fused scores/softmax/attn/gate/normalize (overwrites d_out in place)
  epilogue<<<BATCH, 256, 0, stream>>>(query, key, value, Wa, ba,
                                      (const float*)d_out, (float*)d_out);
}

// Round 2
// 245.595 us; speedup vs baseline: 1.1689x; 1.1689x over previous
//
#include <hip/hip_runtime.h>
#include <hip/hip_bf16.h>

#define DIM   1024
#define BATCH 8192
#define KV    16

typedef __attribute__((ext_vector_type(4))) float f32x4;
typedef __attribute__((ext_vector_type(8))) short short8;

static __device__ __forceinline__ unsigned short f2bf(float x) {
  return __builtin_bit_cast(unsigned short, __float2bfloat16(x));
}
static __device__ __forceinline__ float bf2f(unsigned short x) {
  return __bfloat162float(__builtin_bit_cast(__hip_bfloat16, x));
}
static __device__ __forceinline__ float dot4(f32x4 a, f32x4 b) {
  return a.x * b.x + a.y * b.y + a.z * b.z + a.w * b.w;
}

static __device__ __forceinline__ void gl_lds16(const unsigned short* g, unsigned short* l) {
  __builtin_amdgcn_global_load_lds(
      (const __attribute__((address_space(1))) void*)g,
      (__attribute__((address_space(3))) void*)l, 16, 0, 0);
}

// ---------------- kernel 1: query f32 -> bf16 ----------------
__global__ __launch_bounds__(256) void convert_q(const f32x4* __restrict__ in,
                                                 ushort4* __restrict__ out, int n4) {
  int i = blockIdx.x * blockDim.x + threadIdx.x;
  int stride = gridDim.x * blockDim.x;
  for (; i < n4; i += stride) {
    f32x4 f = in[i];
    ushort4 o;
    o.x = f2bf(f.x); o.y = f2bf(f.y); o.z = f2bf(f.z); o.w = f2bf(f.w);
    out[i] = o;
  }
}

// ---------------- kernel 2: Wq,Wk f32 -> transposed bf16 ----------------
__global__ __launch_bounds__(256) void transpose_w(const float* __restrict__ Wq,
                                                   const float* __restrict__ Wk,
                                                   unsigned short* __restrict__ WqT,
                                                   unsigned short* __restrict__ WkT) {
  __shared__ float tile[32][33];
  const float* src = blockIdx.z ? Wk : Wq;
  unsigned short* dst = blockIdx.z ? WkT : WqT;
  int x = blockIdx.x * 32 + threadIdx.x;
  int y0 = blockIdx.y * 32;
  #pragma unroll
  for (int i = threadIdx.y; i < 32; i += 8)
    tile[i][threadIdx.x] = src[(size_t)(y0 + i) * DIM + x];
  __syncthreads();
  int x2 = blockIdx.y * 32 + threadIdx.x;
  int y2 = blockIdx.x * 32;
  #pragma unroll
  for (int i = threadIdx.y; i < 32; i += 8)
    dst[(size_t)(y2 + i) * DIM + x2] = f2bf(tile[threadIdx.x][i]);
}

// ---------------- kernel 3: Mt = WkT x WqT^T, 64x64 tiles (256 blocks) ----------------
__global__ __launch_bounds__(256) void gemm_nt64(const unsigned short* __restrict__ A,
                                                 const unsigned short* __restrict__ B,
                                                 unsigned short* __restrict__ C,
                                                 int N, int K) {
  __shared__ __align__(16) unsigned short As[64 * 32];
  __shared__ __align__(16) unsigned short Bs[64 * 32];
  const int tid = threadIdx.x;
  const int lane = tid & 63;
  const int wave = tid >> 6;
  const int wr = wave >> 1, wc = wave & 1;
  const size_t bm = (size_t)blockIdx.x * 64;
  const size_t bn = (size_t)blockIdx.y * 64;

  f32x4 acc[2][2];
  #pragma unroll
  for (int m = 0; m < 2; ++m)
    #pragma unroll
    for (int n = 0; n < 2; ++n)
      acc[m][n] = (f32x4){0.f, 0.f, 0.f, 0.f};

  const int r0 = tid >> 2;
  const int cc = (tid & 3) * 8;
  const int kg = lane >> 4;
  const int rowf = lane & 15;

  for (int kt = 0; kt < K; kt += 32) {
    gl_lds16(A + (bm + r0) * K + kt + cc, As + tid * 8);
    gl_lds16(B + (bn + r0) * K + kt + cc, Bs + tid * 8);
    __syncthreads();
    short8 af[2], bfr[2];
    #pragma unroll
    for (int m = 0; m < 2; ++m)
      af[m] = *(const short8*)(As + ((wr * 32 + m * 16 + rowf) * 32 + kg * 8));
    #pragma unroll
    for (int n = 0; n < 2; ++n)
      bfr[n] = *(const short8*)(Bs + ((wc * 32 + n * 16 + rowf) * 32 + kg * 8));
    #pragma unroll
    for (int m = 0; m < 2; ++m)
      #pragma unroll
      for (int n = 0; n < 2; ++n)
        acc[m][n] = __builtin_amdgcn_mfma_f32_16x16x32_bf16(af[m], bfr[n], acc[m][n], 0, 0, 0);
    __syncthreads();
  }

  const int rq = (lane >> 4) * 4;
  const int colf = lane & 15;
  #pragma unroll
  for (int m = 0; m < 2; ++m)
    #pragma unroll
    for (int n = 0; n < 2; ++n)
      #pragma unroll
      for (int i = 0; i < 4; ++i)
        C[(bm + wr * 32 + m * 16 + rq + i) * N + bn + wc * 32 + n * 16 + colf] =
            f2bf(acc[m][n][i]);
}

// ---------------- kernel 4: u = qbf x Mt^T, 128x128 tiles, bf16 out, XCD swizzle ----------
// flat grid, nwg % 8 == 0. C write is STRIDED: row stride ldc (elements).
__global__ __launch_bounds__(256) void gemm_u(const unsigned short* __restrict__ A,
                                              const unsigned short* __restrict__ B,
                                              unsigned short* __restrict__ C,
                                              int K, int ntN, int ldc) {
  // XCD swizzle: hw block b (on XCD b%8) takes logical tile (b%8)*cpx + b/8
  const int cpx = gridDim.x >> 3;
  const int wg = (blockIdx.x & 7) * cpx + (blockIdx.x >> 3);
  const size_t bm = (size_t)(wg / ntN) * 128;
  const size_t bn = (size_t)(wg % ntN) * 128;

  __shared__ __align__(16) unsigned short As[128 * 32];
  __shared__ __align__(16) unsigned short Bs[128 * 32];
  const int tid = threadIdx.x;
  const int lane = tid & 63;
  const int wave = tid >> 6;
  const int wr = wave >> 1, wc = wave & 1;

  f32x4 acc[4][4];
  #pragma unroll
  for (int m = 0; m < 4; ++m)
    #pragma unroll
    for (int n = 0; n < 4; ++n)
      acc[m][n] = (f32x4){0.f, 0.f, 0.f, 0.f};

  const int r0 = tid >> 2;
  const int r1 = 64 + (tid >> 2);
  const int cc = (tid & 3) * 8;
  const int kg = lane >> 4;
  const int rowf = lane & 15;

  for (int kt = 0; kt < K; kt += 32) {
    gl_lds16(A + (bm + r0) * K + kt + cc, As + tid * 8);
    gl_lds16(A + (bm + r1) * K + kt + cc, As + 2048 + tid * 8);
    gl_lds16(B + (bn + r0) * K + kt + cc, Bs + tid * 8);
    gl_lds16(B + (bn + r1) * K + kt + cc, Bs + 2048 + tid * 8);
    __syncthreads();
    short8 af[4], bfr[4];
    #pragma unroll
    for (int m = 0; m < 4; ++m)
      af[m] = *(const short8*)(As + ((wr * 64 + m * 16 + rowf) * 32 + kg * 8));
    #pragma unroll
    for (int n = 0; n < 4; ++n)
      bfr[n] = *(const short8*)(Bs + ((wc * 64 + n * 16 + rowf) * 32 + kg * 8));
    #pragma unroll
    for (int m = 0; m < 4; ++m)
      #pragma unroll
      for (int n = 0; n < 4; ++n)
        acc[m][n] = __builtin_amdgcn_mfma_f32_16x16x32_bf16(af[m], bfr[n], acc[m][n], 0, 0, 0);
    __syncthreads();
  }

  const int rq = (lane >> 4) * 4;
  const int colf = lane & 15;
  #pragma unroll
  for (int m = 0; m < 4; ++m)
    #pragma unroll
    for (int n = 0; n < 4; ++n)
      #pragma unroll
      for (int i = 0; i < 4; ++i) {
        size_t row = bm + wr * 64 + m * 16 + rq + i;
        size_t col = bn + wc * 64 + n * 16 + colf;
        C[row * (size_t)ldc + col] = f2bf(acc[m][n][i]);
      }
}

// ---------------- kernel 5: fused attention epilogue ----------------
// u is bf16, strided: row b at element offset b*2048 (first 1024 of each 2048-elem slot
// inside d_out) -> block b reads exactly the bytes it later overwrites. No cross-block race.
__global__ __launch_bounds__(256) void epilogue(const float* __restrict__ query,
                                                const float* __restrict__ key,
                                                const float* __restrict__ value,
                                                const float* __restrict__ Wa,
                                                const float* __restrict__ ba,
                                                const unsigned short* __restrict__ u,
                                                float* __restrict__ out) {
  const int b = blockIdx.x;
  const int tid = threadIdx.x;
  const int lane = tid & 63, wave = tid >> 6;
  const f32x4* q4 = (const f32x4*)(query + (size_t)b * DIM);
  const f32x4* k4 = (const f32x4*)(key + (size_t)b * KV * DIM);
  const f32x4* v4 = (const f32x4*)(value + (size_t)b * KV * DIM);

  f32x4 qv = q4[tid];
  ushort4 ub = ((const ushort4*)(u + (size_t)b * 2048))[tid];
  f32x4 uv;
  uv.x = bf2f(ub.x); uv.y = bf2f(ub.y); uv.z = bf2f(ub.z); uv.w = bf2f(ub.w);
  f32x4 wv = ((const f32x4*)Wa)[tid];

  float s[17];
  s[0] = dot4(qv, uv);
  float ad = dot4(qv, wv);
  #pragma unroll
  for (int j = 1; j <= 16; ++j) {
    f32x4 kv = __builtin_nontemporal_load(k4 + (j - 1) * 256 + tid);
    s[j] = dot4(uv, kv);
  }

  // prefetch all V rows BEFORE the reduction chains: HBM latency hides under softmax
  f32x4 vv[16];
  #pragma unroll
  for (int j = 0; j < 16; ++j)
    vv[j] = __builtin_nontemporal_load(v4 + j * 256 + tid);

  // wave-level butterfly reduce of 18 scalars
  #pragma unroll
  for (int m = 32; m >= 1; m >>= 1) {
    #pragma unroll
    for (int j = 0; j < 17; ++j) s[j] += __shfl_xor(s[j], m);
    ad += __shfl_xor(ad, m);
  }
  __shared__ float red[4][18];
  if (lane == 0) {
    #pragma unroll
    for (int j = 0; j < 17; ++j) red[wave][j] = s[j];
    red[wave][17] = ad;
  }
  __syncthreads();

  float wt[17];
  float mx = -1e30f;
  #pragma unroll
  for (int j = 0; j < 17; ++j) {
    float t = (red[0][j] + red[1][j] + red[2][j] + red[3][j]) * 0.03125f;
    wt[j] = t;
    mx = fmaxf(mx, t);
  }
  float den = 0.f;
  #pragma unroll
  for (int j = 0; j < 17; ++j) {
    wt[j] = expf(wt[j] - mx);
    den += wt[j];
  }
  float adt = red[0][17] + red[1][17] + red[2][17] + red[3][17] + ba[0];
  float alpha = 1.0f / (1.0f + expf(-adt));
  float am = alpha / den;

  f32x4 acc = qv * wt[0];
  #pragma unroll
  for (int j = 1; j <= 16; ++j) acc += vv[j - 1] * wt[j];
  f32x4 t = qv + acc * am;

  float ssp = dot4(t, t);
  #pragma unroll
  for (int m = 32; m >= 1; m >>= 1) ssp += __shfl_xor(ssp, m);
  __shared__ float red2[4];
  if (lane == 0) red2[wave] = ssp;
  __syncthreads();
  float nrm = sqrtf(red2[0] + red2[1] + red2[2] + red2[3]);
  float inv = 1.0f / fmaxf(nrm, 1e-12f);

  ((f32x4*)(out + (size_t)b * DIM))[tid] = t * inv;
}

// ---------------- launcher ----------------
extern "C" void kernel_launch(void* const* d_in, const int* in_sizes, int n_in,
                              void* d_out, int out_size, void* d_ws, size_t ws_size,
                              hipStream_t stream) {
  const float* query = (const float*)d_in[0];
  const float* key   = (const float*)d_in[1];
  const float* value = (const float*)d_in[2];
  const float* Wq    = (const float*)d_in[3];
  const float* Wk    = (const float*)d_in[4];
  const float* Wa    = (const float*)d_in[5];
  const float* ba    = (const float*)d_in[6];

  unsigned short* qbf = (unsigned short*)d_ws;              // 16 MiB
  unsigned short* WqT = qbf + (size_t)BATCH * DIM;          //  2 MiB
  unsigned short* WkT = WqT + (size_t)DIM * DIM;            //  2 MiB
  unsigned short* Mt  = WkT + (size_t)DIM * DIM;            //  2 MiB
  unsigned short* ubf = (unsigned short*)d_out;             // strided bf16 u inside d_out

  convert_q<<<2048, 256, 0, stream>>>((const f32x4*)query, (ushort4*)qbf, BATCH * DIM / 4);
  transpose_w<<<dim3(32, 32, 2), dim3(32, 8), 0, stream>>>(Wq, Wk, WqT, WkT);
  // Mt = WkT x WqT^T  (1024^3, bf16 out), 64^2 tiles -> 256 blocks
  gemm_nt64<<<dim3(16, 16), 256, 0, stream>>>(WkT, WqT, Mt, DIM, DIM);
  // u = qbf x Mt^T  (8192x1024x1024), bf16 out, strided ldc=2048 into d_out
  gemm_u<<<512, 256, 0, stream>>>(qbf, Mt, ubf, DIM, DIM / 128, 2048);
  // fused scores/softmax/attn/gate/normalize (reads strided bf16 u, writes f32 in place)
  epilogue<<<BATCH, 256, 0, stream>>>(query, key, value, Wa, ba, ubf, (float*)d_out);
}